// Round 1
// baseline (356.054 us; speedup 1.0000x reference)
//
#include <hip/hip_runtime.h>

#define TPB 256
#define RPT 4                    // rows per thread
#define D 5
#define F4PT 5                   // float4 per thread = RPT*D/4
#define F4PB (TPB * F4PT)        // 1280 float4 per block (20 KiB LDS)

__global__ __launch_bounds__(TPB, 4)
void uber_kernel(const float* __restrict__ x,
                 const float* __restrict__ W1,
                 const float* __restrict__ b1,
                 const float* __restrict__ W2,
                 const float* __restrict__ b2,
                 float* __restrict__ out)
{
    __shared__ float4 lds[F4PB];
    const int tid = threadIdx.x;
    const long long base4 = (long long)blockIdx.x * F4PB;

    const float4* __restrict__ src4 = reinterpret_cast<const float4*>(x) + base4;
    float4* __restrict__ dst4 = reinterpret_cast<float4*>(out) + base4;

    // ---- stage in (coalesced float4) ----
    float4 stg[F4PT];
#pragma unroll
    for (int k = 0; k < F4PT; ++k) stg[k] = src4[k * TPB + tid];

    // ---- weights (uniform addresses -> L1-broadcast / s_load) ----
    float w1[D][D], w2[D][D], bb1[D], bb2m4[D];
#pragma unroll
    for (int j = 0; j < D; ++j) {
        bb1[j] = b1[j];
        bb2m4[j] = b2[j] - 4.0f;
#pragma unroll
        for (int k = 0; k < D; ++k) {
            w1[j][k] = W1[j * D + k];
            w2[j][k] = W2[j * D + k];
        }
    }

#pragma unroll
    for (int k = 0; k < F4PT; ++k) lds[k * TPB + tid] = stg[k];
    __syncthreads();

    // ---- each thread pulls its own 4 rows (20 contiguous floats) ----
    float f[RPT * D];
#pragma unroll
    for (int j = 0; j < F4PT; ++j) {
        float4 t = lds[F4PT * tid + j];
        f[4 * j + 0] = t.x; f[4 * j + 1] = t.y;
        f[4 * j + 2] = t.z; f[4 * j + 3] = t.w;
    }

#pragma unroll
    for (int r = 0; r < RPT; ++r) {
        float v[D];
        // preamble ((x+1)*2-1) x3  ==  8x+7 exactly
#pragma unroll
        for (int c = 0; c < D; ++c) v[c] = fmaf(f[r * D + c], 8.0f, 7.0f);

#pragma unroll
        for (int it = 0; it < 3; ++it) {
            float t[D], u[D];
#pragma unroll
            for (int c = 0; c < D; ++c) t[c] = __cosf(v[c]);
            // fc1: u = t @ W1^T + b1
#pragma unroll
            for (int j = 0; j < D; ++j) {
                float acc = bb1[j];
#pragma unroll
                for (int k = 0; k < D; ++k) acc = fmaf(t[k], w1[j][k], acc);
                u[j] = acc;
            }
#pragma unroll
            for (int c = 0; c < D; ++c) t[c] = __sinf(u[c]);
            // two fc2 steps: x = ((x-4)*2) @ W2^T + (b2-4)
#pragma unroll
            for (int s = 0; s < 2; ++s) {
                float p[D];
#pragma unroll
                for (int c = 0; c < D; ++c) p[c] = fmaf(t[c], 2.0f, -8.0f);
#pragma unroll
                for (int j = 0; j < D; ++j) {
                    float acc = bb2m4[j];
#pragma unroll
                    for (int k = 0; k < D; ++k) acc = fmaf(p[k], w2[j][k], acc);
                    u[j] = acc;
                }
#pragma unroll
                for (int c = 0; c < D; ++c) t[c] = u[c];
            }
#pragma unroll
            for (int c = 0; c < D; ++c) t[c] = __logf(t[c]);
            // fc1 again
#pragma unroll
            for (int j = 0; j < D; ++j) {
                float acc = bb1[j];
#pragma unroll
                for (int k = 0; k < D; ++k) acc = fmaf(t[k], w1[j][k], acc);
                v[j] = acc;
            }
        }
        // tanh(6v) = 1 - 2/(exp(12v)+1); exp overflow->inf->1, underflow->0->-1 (correct limits)
#pragma unroll
        for (int c = 0; c < D; ++c) {
            float e = __expf(12.0f * v[c]);
            f[r * D + c] = 1.0f - __fdividef(2.0f, e + 1.0f);
        }
    }

    // ---- results to own LDS slots, then coalesced store-out ----
#pragma unroll
    for (int j = 0; j < F4PT; ++j)
        lds[F4PT * tid + j] = make_float4(f[4 * j + 0], f[4 * j + 1],
                                          f[4 * j + 2], f[4 * j + 3]);
    __syncthreads();
#pragma unroll
    for (int k = 0; k < F4PT; ++k) dst4[k * TPB + tid] = lds[k * TPB + tid];
}

extern "C" void kernel_launch(void* const* d_in, const int* in_sizes, int n_in,
                              void* d_out, int out_size, void* d_ws, size_t ws_size,
                              hipStream_t stream) {
    const float* x  = (const float*)d_in[0];
    const float* W1 = (const float*)d_in[1];
    const float* b1 = (const float*)d_in[2];
    const float* W2 = (const float*)d_in[3];
    const float* b2 = (const float*)d_in[4];
    float* out = (float*)d_out;

    const int rows = in_sizes[0] / D;          // 8388608
    const int grid = rows / (TPB * RPT);       // 8192 blocks, exact (2^23 / 1024)
    uber_kernel<<<grid, TPB, 0, stream>>>(x, W1, b1, W2, b2, out);
}

// Round 3
// 292.080 us; speedup vs baseline: 1.2190x; 1.2190x over previous
//
#include <hip/hip_runtime.h>

#define TPB 256
#define RPT 4                    // rows per thread
#define DD 5
#define F4PT 5                   // float4 per thread = RPT*DD/4
#define F4PB (TPB * F4PT)        // 1280 float4 per block (20 KiB LDS)

#define INV2PI 0.15915494309189535f
#define LN2f   0.6931471805599453f
#define C2f    108.79849079439689f   /* 12*2pi/ln2: input scale for last fc1 via W1b */

// Constant block layout in d_ws (floats):
//  [0..24]  W1a = W1 * (1/2pi)        (fc1 feeding sin; bias b1c)
//  [25..49] W1b = W1 * (ln2/2pi)      (fc1 consuming log2 output; bias b1c, or b1t for iter2)
//  [50..74] M   = A^2, A = 2*W2       (fused double-fc2)
//  [75..79] e   = A*d + d, d = b2-4-8*rowsum(W2)
//  [80..84] b1c = b1 * (1/2pi)
//  [85..89] b1t = b1 * (12/ln2)
#define NCST 90

__device__ __forceinline__ void compute_consts(const float* __restrict__ W1,
                                               const float* __restrict__ b1,
                                               const float* __restrict__ W2,
                                               const float* __restrict__ b2,
                                               float* cst)
{
#pragma unroll
    for (int i = 0; i < 25; ++i) {
        float w = W1[i];
        cst[i]      = w * INV2PI;
        cst[25 + i] = w * (LN2f * INV2PI);
    }
    float A[25], dv[DD];
#pragma unroll
    for (int j = 0; j < DD; ++j) {
        float s = 0.0f;
#pragma unroll
        for (int k = 0; k < DD; ++k) {
            float w = W2[j * DD + k];
            A[j * DD + k] = 2.0f * w;
            s += w;
        }
        dv[j] = b2[j] - 4.0f - 8.0f * s;
    }
#pragma unroll
    for (int j = 0; j < DD; ++j)
#pragma unroll
        for (int k = 0; k < DD; ++k) {
            float acc = 0.0f;
#pragma unroll
            for (int m = 0; m < DD; ++m) acc = fmaf(A[j * DD + m], A[m * DD + k], acc);
            cst[50 + j * DD + k] = acc;
        }
#pragma unroll
    for (int j = 0; j < DD; ++j) {
        float acc = dv[j];
#pragma unroll
        for (int m = 0; m < DD; ++m) acc = fmaf(A[j * DD + m], dv[m], acc);
        cst[75 + j] = acc;
    }
#pragma unroll
    for (int j = 0; j < DD; ++j) {
        cst[80 + j] = b1[j] * INV2PI;
        cst[85 + j] = b1[j] * (12.0f / LN2f);
    }
}

__global__ void prep_kernel(const float* __restrict__ W1, const float* __restrict__ b1,
                            const float* __restrict__ W2, const float* __restrict__ b2,
                            float* __restrict__ cst)
{
    if (threadIdx.x == 0 && blockIdx.x == 0) {
        float c[NCST];
        compute_consts(W1, b1, W2, b2, c);
        for (int i = 0; i < NCST; ++i) cst[i] = c[i];
    }
}

// Process one row of 5 values in-place. All transcendentals are single raw
// instructions; all scale factors are pre-folded into the weight constants.
__device__ __forceinline__ void process_row(float* f,
                                            const float* w1a, const float* w1b,
                                            const float* m,   const float* ev,
                                            const float* b1c, const float* b1t)
{
    float v[DD], t[DD], u[DD];
    // preamble ((x+1)*2-1)x3 == 8x+7, pre-divided by 2pi for v_cos (revolutions)
#pragma unroll
    for (int c = 0; c < DD; ++c) v[c] = fmaf(f[c], 8.0f * INV2PI, 7.0f * INV2PI);

#pragma unroll
    for (int it = 0; it < 3; ++it) {
#pragma unroll
        for (int c = 0; c < DD; ++c) t[c] = __builtin_amdgcn_cosf(v[c]);
        // fc1 (sin-feeding): u = t @ W1a^T + b1c  -> sin revolutions
#pragma unroll
        for (int j = 0; j < DD; ++j) {
            float acc = b1c[j];
#pragma unroll
            for (int k = 0; k < DD; ++k) acc = fmaf(t[k], w1a[j * DD + k], acc);
            u[j] = acc;
        }
#pragma unroll
        for (int c = 0; c < DD; ++c) t[c] = __builtin_amdgcn_sinf(u[c]);
        // fused double-fc2: u = t @ M^T + e   (log input, stays positive)
#pragma unroll
        for (int j = 0; j < DD; ++j) {
            float acc = ev[j];
#pragma unroll
            for (int k = 0; k < DD; ++k) acc = fmaf(t[k], m[j * DD + k], acc);
            u[j] = acc;
        }
#pragma unroll
        for (int c = 0; c < DD; ++c) t[c] = __builtin_amdgcn_logf(u[c]);  // log2
        if (it < 2) {
            // fc1 consuming log2 output, result pre-scaled to cos revolutions
#pragma unroll
            for (int j = 0; j < DD; ++j) {
                float acc = b1c[j];
#pragma unroll
                for (int k = 0; k < DD; ++k) acc = fmaf(t[k], w1b[j * DD + k], acc);
                v[j] = acc;
            }
        } else {
            // last fc1, result pre-scaled to exp2 input: z = (12/ln2)*(ln(y)@W1^T + b1)
#pragma unroll
            for (int c = 0; c < DD; ++c) t[c] *= C2f;
#pragma unroll
            for (int j = 0; j < DD; ++j) {
                float acc = b1t[j];
#pragma unroll
                for (int k = 0; k < DD; ++k) acc = fmaf(t[k], w1b[j * DD + k], acc);
                v[j] = acc;
            }
        }
    }
    // tanh(6x) = 1 - 2/(exp2(z)+1); overflow->1, underflow->-1 (correct limits)
#pragma unroll
    for (int c = 0; c < DD; ++c) {
        float e2 = __builtin_amdgcn_exp2f(v[c]);
        f[c] = fmaf(__builtin_amdgcn_rcpf(e2 + 1.0f), -2.0f, 1.0f);
    }
}

template <bool LOCAL_CST>
__device__ __forceinline__ void uber_body(const float* __restrict__ x,
                                          const float* __restrict__ cstg,
                                          const float* __restrict__ W1,
                                          const float* __restrict__ b1,
                                          const float* __restrict__ W2,
                                          const float* __restrict__ b2,
                                          float* __restrict__ out)
{
    __shared__ float4 lds[F4PB];
    const int tid = threadIdx.x;
    const long long base4 = (long long)blockIdx.x * F4PB;

    const float4* __restrict__ src4 = reinterpret_cast<const float4*>(x) + base4;
    float4* __restrict__ dst4 = reinterpret_cast<float4*>(out) + base4;

    // ---- stage in (coalesced float4) ----
    float4 stg[F4PT];
#pragma unroll
    for (int k = 0; k < F4PT; ++k) stg[k] = src4[k * TPB + tid];

    // ---- constants ----
    float lc[LOCAL_CST ? NCST : 1];
    const float* cst;
    if (LOCAL_CST) {
        compute_consts(W1, b1, W2, b2, lc);
        cst = lc;
    } else {
        cst = cstg;   // uniform addresses -> s_load, weights SGPR-resident
    }
    float w1a[25], w1b[25], m[25], ev[DD], b1c[DD], b1t[DD];
#pragma unroll
    for (int i = 0; i < 25; ++i) { w1a[i] = cst[i]; w1b[i] = cst[25 + i]; m[i] = cst[50 + i]; }
#pragma unroll
    for (int i = 0; i < DD; ++i) { ev[i] = cst[75 + i]; b1c[i] = cst[80 + i]; b1t[i] = cst[85 + i]; }

#pragma unroll
    for (int k = 0; k < F4PT; ++k) lds[k * TPB + tid] = stg[k];
    __syncthreads();

    float f[RPT * DD];
#pragma unroll
    for (int j = 0; j < F4PT; ++j) {
        float4 t = lds[F4PT * tid + j];
        f[4 * j + 0] = t.x; f[4 * j + 1] = t.y;
        f[4 * j + 2] = t.z; f[4 * j + 3] = t.w;
    }

#pragma unroll
    for (int r = 0; r < RPT; ++r) process_row(f + r * DD, w1a, w1b, m, ev, b1c, b1t);

#pragma unroll
    for (int j = 0; j < F4PT; ++j)
        lds[F4PT * tid + j] = make_float4(f[4 * j + 0], f[4 * j + 1],
                                          f[4 * j + 2], f[4 * j + 3]);
    __syncthreads();
#pragma unroll
    for (int k = 0; k < F4PT; ++k) dst4[k * TPB + tid] = lds[k * TPB + tid];
}

__global__ __launch_bounds__(TPB, 4)
void uber_main(const float* __restrict__ x, const float* __restrict__ cst,
               float* __restrict__ out)
{
    uber_body<false>(x, cst, nullptr, nullptr, nullptr, nullptr, out);
}

__global__ void uber_local(const float* __restrict__ x,
                           const float* __restrict__ W1, const float* __restrict__ b1,
                           const float* __restrict__ W2, const float* __restrict__ b2,
                           float* __restrict__ out)
{
    uber_body<true>(x, nullptr, W1, b1, W2, b2, out);
}

extern "C" void kernel_launch(void* const* d_in, const int* in_sizes, int n_in,
                              void* d_out, int out_size, void* d_ws, size_t ws_size,
                              hipStream_t stream) {
    const float* x  = (const float*)d_in[0];
    const float* W1 = (const float*)d_in[1];
    const float* b1 = (const float*)d_in[2];
    const float* W2 = (const float*)d_in[3];
    const float* b2 = (const float*)d_in[4];
    float* out = (float*)d_out;

    const int rows = in_sizes[0] / DD;         // 8388608
    const int grid = rows / (TPB * RPT);       // 8192 blocks, exact

    if (ws_size >= NCST * sizeof(float)) {
        float* cst = (float*)d_ws;
        prep_kernel<<<1, 64, 0, stream>>>(W1, b1, W2, b2, cst);
        uber_main<<<grid, TPB, 0, stream>>>(x, cst, out);
    } else {
        uber_local<<<grid, TPB, 0, stream>>>(x, W1, b1, W2, b2, out);
    }
}